// Round 1
// baseline (1342.288 us; speedup 1.0000x reference)
//
#include <hip/hip_runtime.h>
#include <math.h>

#pragma clang fp contract(off)

#define NLVL 5
#define TOTALN 261888
#define NBATCH 16
#define CAP 1024
#define NPROB (NBATCH * NLVL)
#define POST_N 1000
#define NMS_TH 0.7f
#define MINSZ 1e-3f
#define IMGSZ 1024.0f
#define BBOX_CLIP 4.135166556742356f

__constant__ int c_loff[NLVL] = {0, 196608, 245760, 258048, 261120};
__constant__ int c_num[NLVL]  = {196608, 49152, 12288, 3072, 768};
__constant__ int c_k[NLVL]    = {1000, 1000, 1000, 1000, 768};

__device__ __forceinline__ unsigned monokey(float f) {
    unsigned b = __float_as_uint(f);
    return (b & 0x80000000u) ? ~b : (b | 0x80000000u);
}

// ---------------- top-k per (image, level): exact radix select + bitonic sort ----------------
__global__ __launch_bounds__(256) void topk_kernel(const float* __restrict__ obj_all,
                                                   unsigned* __restrict__ sel) {
    __shared__ unsigned hist[2048];
    __shared__ unsigned long long skey[CAP];
    __shared__ unsigned eqbuf[1024];
    __shared__ int s_b, s_need, s_cntGT, s_cntEQ;

    const int p = blockIdx.x;
    const int img = p / NLVL, lvl = p % NLVL;
    const int n = c_num[lvl], k = c_k[lvl];
    const int tid = threadIdx.x;
    const float* obj = obj_all + (size_t)img * TOTALN + c_loff[lvl];

    if (k >= n) {
        for (int r = tid; r < CAP; r += 256)
            skey[r] = (r < n)
                ? ((((unsigned long long)monokey(obj[r])) << 32) | (unsigned)(~(unsigned)r))
                : 0ull;
        __syncthreads();
    } else {
        // ---- pass 1: bits [31:21]
        for (int i = tid; i < 2048; i += 256) hist[i] = 0;
        __syncthreads();
        for (int i = tid; i < n; i += 256) atomicAdd(&hist[monokey(obj[i]) >> 21], 1u);
        __syncthreads();
        if (tid == 0) {
            unsigned need = (unsigned)k, acc = 0; int bsel = 0;
            for (int b = 2047; b >= 0; --b) {
                unsigned c = hist[b];
                if (acc + c >= need) { bsel = b; break; }
                acc += c;
            }
            s_b = bsel; s_need = (int)(need - acc);
        }
        __syncthreads();
        const int b1 = s_b; const int need2 = s_need;
        __syncthreads();
        // ---- pass 2: bits [20:10] within b1
        for (int i = tid; i < 2048; i += 256) hist[i] = 0;
        __syncthreads();
        for (int i = tid; i < n; i += 256) {
            unsigned key = monokey(obj[i]);
            if ((int)(key >> 21) == b1) atomicAdd(&hist[(key >> 10) & 0x7FFu], 1u);
        }
        __syncthreads();
        if (tid == 0) {
            unsigned need = (unsigned)need2, acc = 0; int bsel = 0;
            for (int b = 2047; b >= 0; --b) {
                unsigned c = hist[b];
                if (acc + c >= need) { bsel = b; break; }
                acc += c;
            }
            s_b = bsel; s_need = (int)(need - acc);
        }
        __syncthreads();
        const int b2 = s_b; const int need3 = s_need;
        __syncthreads();
        // ---- pass 3: bits [9:0] within (b1,b2)
        for (int i = tid; i < 2048; i += 256) hist[i] = 0;
        __syncthreads();
        const unsigned pre22 = (((unsigned)b1 << 11) | (unsigned)b2);
        for (int i = tid; i < n; i += 256) {
            unsigned key = monokey(obj[i]);
            if ((key >> 10) == pre22) atomicAdd(&hist[key & 0x3FFu], 1u);
        }
        __syncthreads();
        if (tid == 0) {
            unsigned need = (unsigned)need3, acc = 0; int bsel = 0;
            for (int b = 1023; b >= 0; --b) {
                unsigned c = hist[b];
                if (acc + c >= need) { bsel = b; break; }
                acc += c;
            }
            s_b = bsel; s_need = (int)(need - acc);
            s_cntGT = 0; s_cntEQ = 0;
        }
        __syncthreads();
        const unsigned T = ((unsigned)b1 << 21) | ((unsigned)b2 << 10) | (unsigned)s_b;
        const int needEq = s_need;
        // ---- compaction
        for (int i = tid; i < n; i += 256) {
            unsigned key = monokey(obj[i]);
            if (key > T) {
                int pos = atomicAdd(&s_cntGT, 1);
                if (pos < CAP)
                    skey[pos] = (((unsigned long long)key) << 32) | (unsigned)(~(unsigned)i);
            } else if (key == T) {
                int e = atomicAdd(&s_cntEQ, 1);
                if (e < 1024) eqbuf[e] = (unsigned)i;
            }
        }
        __syncthreads();
        if (tid == 0) {
            int cntGT = s_cntGT; if (cntGT > CAP) cntGT = CAP;
            int m = s_cntEQ; if (m > 1024) m = 1024;
            int take = needEq < m ? needEq : m;
            for (int t = 0; t < take; ++t) {      // partial selection: smallest indices first
                int best = t;
                for (int u = t + 1; u < m; ++u)
                    if (eqbuf[u] < eqbuf[best]) best = u;
                unsigned tmp = eqbuf[t]; eqbuf[t] = eqbuf[best]; eqbuf[best] = tmp;
                if (cntGT + t < CAP)
                    skey[cntGT + t] = (((unsigned long long)T) << 32) | (unsigned)(~eqbuf[t]);
            }
            s_cntGT = cntGT + take;
        }
        __syncthreads();
        const int filled = s_cntGT;
        for (int r = tid; r < CAP; r += 256)
            if (r >= filled) skey[r] = 0ull;
        __syncthreads();
    }

    // ---- bitonic sort, descending (key desc, then original index asc via ~idx)
    for (int kk = 2; kk <= CAP; kk <<= 1) {
        for (int j = kk >> 1; j > 0; j >>= 1) {
            for (int i = tid; i < CAP; i += 256) {
                int ixj = i ^ j;
                if (ixj > i) {
                    unsigned long long a = skey[i], b = skey[ixj];
                    bool up = ((i & kk) != 0);
                    if ((a > b) == up) { skey[i] = b; skey[ixj] = a; }
                }
            }
            __syncthreads();
        }
    }

    const int base = p * CAP;
    for (int r = tid; r < k; r += 256) {
        unsigned li = ~(unsigned)(skey[r] & 0xFFFFFFFFull);
        sel[base + r] = (unsigned)c_loff[lvl] + li;
    }
}

// ---------------- decode + clip + validity + sigmoid ----------------
__global__ __launch_bounds__(256) void decode_kernel(
    const float* __restrict__ obj_all, const float* __restrict__ deltas,
    const float* __restrict__ anchors, const unsigned* __restrict__ sel,
    float* __restrict__ cx1, float* __restrict__ cy1,
    float* __restrict__ cx2, float* __restrict__ cy2, float* __restrict__ csc) {
    int g = blockIdx.x * 256 + threadIdx.x;
    if (g >= NPROB * CAP) return;
    int p = g >> 10, r = g & (CAP - 1);
    int img = p / NLVL, lvl = p % NLVL;
    int k = c_k[lvl];
    float x1 = 0.f, y1 = 0.f, x2 = 0.f, y2 = 0.f, scv = -1.0f;
    if (r < k) {
        unsigned idx = sel[p * CAP + r];
        if (idx < (unsigned)TOTALN) {
            float o = obj_all[(size_t)img * TOTALN + idx];
            const float* dd = deltas + ((size_t)img * TOTALN + (size_t)idx) * 4;
            const float* aa = anchors + (size_t)idx * 4;
            float a0 = aa[0], a1 = aa[1], a2 = aa[2], a3 = aa[3];
            float w = a2 - a0, h = a3 - a1;
            float cx = a0 + 0.5f * w, cy = a1 + 0.5f * h;
            float dx = dd[0], dy = dd[1];
            float dw = fminf(dd[2], BBOX_CLIP), dh = fminf(dd[3], BBOX_CLIP);
            float pcx = dx * w + cx, pcy = dy * h + cy;
            float pw = expf(dw) * w, ph = expf(dh) * h;
            float bx1 = pcx - 0.5f * pw, by1 = pcy - 0.5f * ph;
            float bx2 = pcx + 0.5f * pw, by2 = pcy + 0.5f * ph;
            x1 = fminf(fmaxf(bx1, 0.f), IMGSZ);
            y1 = fminf(fmaxf(by1, 0.f), IMGSZ);
            x2 = fminf(fmaxf(bx2, 0.f), IMGSZ);
            y2 = fminf(fmaxf(by2, 0.f), IMGSZ);
            float wsz = x2 - x1, hsz = y2 - y1;
            if (wsz >= MINSZ && hsz >= MINSZ) scv = 1.0f / (1.0f + expf(-o));
        }
    }
    cx1[g] = x1; cy1[g] = y1; cx2[g] = x2; cy2[g] = y2; csc[g] = scv;
}

// ---------------- per-(image,level) greedy NMS: accept + kill ----------------
__global__ __launch_bounds__(256) void nms_kernel(
    const float* __restrict__ cx1, const float* __restrict__ cy1,
    const float* __restrict__ cx2, const float* __restrict__ cy2,
    const float* __restrict__ csc,
    float* __restrict__ svbox, float* __restrict__ svsc, int* __restrict__ svcnt) {
    __shared__ float sx1[CAP], sy1[CAP], sx2[CAP], sy2[CAP], ssc[CAP];
    __shared__ unsigned short survL[CAP];
    __shared__ int wmin[4];

    const int p = blockIdx.x, tid = threadIdx.x;
    const int base = p * CAP;
    for (int i = tid; i < CAP; i += 256) {
        sx1[i] = cx1[base + i]; sy1[i] = cy1[base + i];
        sx2[i] = cx2[base + i]; sy2[i] = cy2[base + i];
        ssc[i] = csc[base + i];
    }
    __syncthreads();

    float bx1[4], by1[4], bx2[4], by2[4];
    unsigned alive = 0;
#pragma unroll
    for (int s = 0; s < 4; ++s) {
        int r = tid * 4 + s;
        bx1[s] = sx1[r]; by1[s] = sy1[r]; bx2[s] = sx2[r]; by2[s] = sy2[r];
        if (ssc[r] > 0.f) alive |= (1u << s);
    }
    const int lane = tid & 63, wid = tid >> 6;
    int nS = 0;

    while (true) {
        unsigned long long ball = __ballot(alive != 0);
        int wj = 0x7FFFFFFF;
        if (ball) {
            int lead = __ffsll((unsigned long long)ball) - 1;
            int myfirst = alive ? (__ffs(alive) - 1) : 0;
            int slot = __shfl(myfirst, lead);
            wj = ((wid << 6) + lead) * 4 + slot;
        }
        if (lane == 0) wmin[wid] = wj;
        __syncthreads();
        int j = min(min(wmin[0], wmin[1]), min(wmin[2], wmin[3]));
        if (j == 0x7FFFFFFF) break;
        if (tid == 0) survL[nS] = (unsigned short)j;
        nS++;
        if (tid == (j >> 2)) alive &= ~(1u << (j & 3));
        float jx1 = sx1[j], jy1 = sy1[j], jx2 = sx2[j], jy2 = sy2[j];
        float jarea = (jx2 - jx1) * (jy2 - jy1);
#pragma unroll
        for (int s = 0; s < 4; ++s) {
            if (alive & (1u << s)) {
                float ltx = fmaxf(jx1, bx1[s]), lty = fmaxf(jy1, by1[s]);
                float rbx = fminf(jx2, bx2[s]), rby = fminf(jy2, by2[s]);
                float wx = fmaxf(rbx - ltx, 0.f), wy = fmaxf(rby - lty, 0.f);
                float inter = wx * wy;
                float ba = (bx2[s] - bx1[s]) * (by2[s] - by1[s]);
                float iou = inter / (jarea + ba - inter);
                if (iou > NMS_TH) alive &= ~(1u << s);
            }
        }
        __syncthreads();
    }

    for (int i = tid; i < nS; i += 256) {
        int r = survL[i];
        int o = base + i;
        svsc[o] = ssc[r];
        svbox[(size_t)o * 4 + 0] = sx1[r];
        svbox[(size_t)o * 4 + 1] = sy1[r];
        svbox[(size_t)o * 4 + 2] = sx2[r];
        svbox[(size_t)o * 4 + 3] = sy2[r];
    }
    if (tid == 0) svcnt[p] = nS;
}

// ---------------- merge 5 survivor lists per image by score (ties -> lower level) ----------------
__global__ __launch_bounds__(256) void merge_kernel(
    const float* __restrict__ svbox, const float* __restrict__ svsc,
    const int* __restrict__ svcnt, float* __restrict__ out) {
    __shared__ float sls[NLVL][CAP];
    __shared__ int scnt[NLVL];
    const int img = blockIdx.x, tid = threadIdx.x;
    if (tid < NLVL) scnt[tid] = svcnt[img * NLVL + tid];
    __syncthreads();
    for (int l = 0; l < NLVL; ++l) {
        int c = scnt[l];
        for (int i = tid; i < c; i += 256) sls[l][i] = svsc[(img * NLVL + l) * CAP + i];
    }
    __syncthreads();
    for (int l = 0; l < NLVL; ++l) {
        int c = scnt[l];
        for (int i = tid; i < c; i += 256) {
            float s = sls[l][i];
            int pos = i;
            for (int m = 0; m < NLVL; ++m) {
                if (m == l) continue;
                int n2 = scnt[m];
                int lo = 0, hi = n2;
                if (m < l) {
                    while (lo < hi) { int mid = (lo + hi) >> 1; if (sls[m][mid] >= s) lo = mid + 1; else hi = mid; }
                } else {
                    while (lo < hi) { int mid = (lo + hi) >> 1; if (sls[m][mid] > s)  lo = mid + 1; else hi = mid; }
                }
                pos += lo;
            }
            if (pos < POST_N) {
                int src = (img * NLVL + l) * CAP + i;
                float* o = out + ((size_t)img * POST_N + pos) * 5;
                o[0] = svbox[(size_t)src * 4 + 0];
                o[1] = svbox[(size_t)src * 4 + 1];
                o[2] = svbox[(size_t)src * 4 + 2];
                o[3] = svbox[(size_t)src * 4 + 3];
                o[4] = s;
            }
        }
    }
}

extern "C" void kernel_launch(void* const* d_in, const int* in_sizes, int n_in,
                              void* d_out, int out_size, void* d_ws, size_t ws_size,
                              hipStream_t stream) {
    const float* obj     = (const float*)d_in[0];
    const float* deltas  = (const float*)d_in[1];
    const float* anchors = (const float*)d_in[2];
    float* out = (float*)d_out;

    char* w = (char*)d_ws;
    size_t off = 0;
    auto alloc = [&](size_t bytes) -> void* {
        void* pp = w + off;
        off += (bytes + 511) & ~(size_t)511;
        return pp;
    };
    unsigned* sel = (unsigned*)alloc((size_t)NPROB * CAP * 4);
    float* cx1 = (float*)alloc((size_t)NPROB * CAP * 4);
    float* cy1 = (float*)alloc((size_t)NPROB * CAP * 4);
    float* cx2 = (float*)alloc((size_t)NPROB * CAP * 4);
    float* cy2 = (float*)alloc((size_t)NPROB * CAP * 4);
    float* csc = (float*)alloc((size_t)NPROB * CAP * 4);
    float* svbox = (float*)alloc((size_t)NPROB * CAP * 16);
    float* svsc  = (float*)alloc((size_t)NPROB * CAP * 4);
    int*   svcnt = (int*)alloc((size_t)NPROB * 4);
    if (off > ws_size) return;  // fail cleanly (output stays poisoned -> visible failure)

    hipMemsetAsync(d_out, 0, (size_t)out_size * sizeof(float), stream);
    topk_kernel<<<NPROB, 256, 0, stream>>>(obj, sel);
    decode_kernel<<<(NPROB * CAP) / 256, 256, 0, stream>>>(obj, deltas, anchors, sel,
                                                           cx1, cy1, cx2, cy2, csc);
    nms_kernel<<<NPROB, 256, 0, stream>>>(cx1, cy1, cx2, cy2, csc, svbox, svsc, svcnt);
    merge_kernel<<<NBATCH, 256, 0, stream>>>(svbox, svsc, svcnt, out);
}

// Round 2
// 762.161 us; speedup vs baseline: 1.7612x; 1.7612x over previous
//
#include <hip/hip_runtime.h>
#include <math.h>

#pragma clang fp contract(off)

#define NLVL 5
#define TOTALN 261888
#define NBATCH 16
#define CAP 1024
#define NPROB (NBATCH * NLVL)
#define POST_N 1000
#define NMS_TH 0.7f
#define MINSZ 1e-3f
#define IMGSZ 1024.0f
#define BBOX_CLIP 4.135166556742356f

#define HBINS 2048
#define CCAP 4096
#define NCHUNK 256   // ceil(261888/1024); level offsets are all multiples of 1024

__constant__ int c_loff[NLVL] = {0, 196608, 245760, 258048, 261120};
__constant__ int c_num[NLVL]  = {196608, 49152, 12288, 3072, 768};
__constant__ int c_k[NLVL]    = {1000, 1000, 1000, 1000, 768};

__device__ __forceinline__ unsigned monokey(float f) {
    unsigned b = __float_as_uint(f);
    return (b & 0x80000000u) ? ~b : (b | 0x80000000u);
}

__device__ __forceinline__ int lvl_of_start(int start) {
    return (start >= 261120) ? 4 : (start >= 258048) ? 3 : (start >= 245760) ? 2
         : (start >= 196608) ? 1 : 0;
}

// ---------------- pass 1: per-chunk LDS histogram of top-11 key bits ----------------
__global__ __launch_bounds__(256) void hist_kernel(const float* __restrict__ obj_all,
                                                   unsigned* __restrict__ ghist) {
    __shared__ unsigned lh[HBINS];
    const int tid = threadIdx.x;
    const int chunk = blockIdx.x;
    const int img = chunk >> 8, c = chunk & 255;
    const int start = c << 10;
    const int lvl = lvl_of_start(start);
    const int nrem = min(1024, TOTALN - start);
    for (int i = tid; i < HBINS; i += 256) lh[i] = 0;
    __syncthreads();
    const float* o = obj_all + (size_t)img * TOTALN + start;
    for (int i = tid; i < nrem; i += 256) atomicAdd(&lh[monokey(o[i]) >> 21], 1u);
    __syncthreads();
    unsigned* gh = ghist + (size_t)(img * NLVL + lvl) * HBINS;
    for (int i = tid; i < HBINS; i += 256) {
        unsigned v = lh[i];
        if (v) atomicAdd(&gh[i], v);
    }
}

// ---------------- pick threshold bucket b1 per problem (suffix-sum of hist) ----------------
__global__ __launch_bounds__(256) void pick1_kernel(const unsigned* __restrict__ ghist,
                                                    unsigned* __restrict__ b1out) {
    __shared__ unsigned suf[HBINS];
    const int p = blockIdx.x, tid = threadIdx.x;
    const int k = c_k[p % NLVL];
    const unsigned* gh = ghist + (size_t)p * HBINS;
    for (int i = tid; i < HBINS; i += 256) suf[i] = gh[i];
    __syncthreads();
    for (int d = 1; d < HBINS; d <<= 1) {
        unsigned v[HBINS / 256];
#pragma unroll
        for (int r = 0; r < HBINS / 256; ++r) {
            int i = tid + r * 256;
            v[r] = suf[i] + ((i + d < HBINS) ? suf[i + d] : 0u);
        }
        __syncthreads();
#pragma unroll
        for (int r = 0; r < HBINS / 256; ++r) suf[tid + r * 256] = v[r];
        __syncthreads();
    }
#pragma unroll
    for (int r = 0; r < HBINS / 256; ++r) {
        int i = tid + r * 256;
        if (suf[i] >= (unsigned)k && (i == HBINS - 1 || suf[i + 1] < (unsigned)k))
            b1out[p] = (unsigned)i;
    }
}

// ---------------- pass 2: compact all keys >= (b1<<21) ----------------
__global__ __launch_bounds__(256) void compact_kernel(const float* __restrict__ obj_all,
                                                      const unsigned* __restrict__ b1in,
                                                      int* __restrict__ cnt,
                                                      unsigned long long* __restrict__ cand) {
    __shared__ unsigned long long lkey[1024];
    __shared__ int s_lc, s_base;
    const int tid = threadIdx.x;
    const int chunk = blockIdx.x;
    const int img = chunk >> 8, c = chunk & 255;
    const int start = c << 10;
    const int lvl = lvl_of_start(start);
    const int nrem = min(1024, TOTALN - start);
    const int p = img * NLVL + lvl;
    const unsigned thr = b1in[p] << 21;
    const int local0 = start - c_loff[lvl];
    if (tid == 0) s_lc = 0;
    __syncthreads();
    const float* o = obj_all + (size_t)img * TOTALN + start;
    for (int i = tid; i < nrem; i += 256) {
        unsigned key = monokey(o[i]);
        if (key >= thr) {
            int l = atomicAdd(&s_lc, 1);
            lkey[l] = (((unsigned long long)key) << 32) | (unsigned)(~(unsigned)(local0 + i));
        }
    }
    __syncthreads();
    if (tid == 0) s_base = atomicAdd(&cnt[p], s_lc);
    __syncthreads();
    const int lc = s_lc, base = s_base;
    unsigned long long* cd = cand + (size_t)p * CCAP;
    for (int i = tid; i < lc; i += 256) {
        int pos = base + i;
        if (pos < CCAP) cd[pos] = lkey[i];
    }
}

// ---------------- finalize: sort candidates, emit exact top-k indices ----------------
__global__ __launch_bounds__(256) void finalize_kernel(const unsigned long long* __restrict__ cand,
                                                       const int* __restrict__ cnt,
                                                       unsigned* __restrict__ sel) {
    __shared__ unsigned long long skey[CCAP];
    const int p = blockIdx.x, tid = threadIdx.x;
    const int lvl = p % NLVL, k = c_k[lvl];
    int n = cnt[p]; if (n > CCAP) n = CCAP;
    const unsigned long long* cd = cand + (size_t)p * CCAP;
    for (int i = tid; i < CCAP; i += 256) skey[i] = (i < n) ? cd[i] : 0ull;
    __syncthreads();
    for (int kk = 2; kk <= CCAP; kk <<= 1) {
        for (int j = kk >> 1; j > 0; j >>= 1) {
            for (int i = tid; i < CCAP; i += 256) {
                int ixj = i ^ j;
                if (ixj > i) {
                    unsigned long long a = skey[i], b = skey[ixj];
                    bool up = ((i & kk) != 0);
                    if ((a > b) == up) { skey[i] = b; skey[ixj] = a; }
                }
            }
            __syncthreads();
        }
    }
    const int base = p * CAP;
    for (int r = tid; r < k; r += 256) {
        unsigned li = ~(unsigned)(skey[r] & 0xFFFFFFFFull);
        sel[base + r] = (unsigned)c_loff[lvl] + li;
    }
}

// ---------------- decode + clip + validity + sigmoid ----------------
__global__ __launch_bounds__(256) void decode_kernel(
    const float* __restrict__ obj_all, const float* __restrict__ deltas,
    const float* __restrict__ anchors, const unsigned* __restrict__ sel,
    float* __restrict__ cx1, float* __restrict__ cy1,
    float* __restrict__ cx2, float* __restrict__ cy2, float* __restrict__ csc) {
    int g = blockIdx.x * 256 + threadIdx.x;
    if (g >= NPROB * CAP) return;
    int p = g >> 10, r = g & (CAP - 1);
    int img = p / NLVL, lvl = p % NLVL;
    int k = c_k[lvl];
    float x1 = 0.f, y1 = 0.f, x2 = 0.f, y2 = 0.f, scv = -1.0f;
    if (r < k) {
        unsigned idx = sel[p * CAP + r];
        if (idx < (unsigned)TOTALN) {
            float o = obj_all[(size_t)img * TOTALN + idx];
            const float* dd = deltas + ((size_t)img * TOTALN + (size_t)idx) * 4;
            const float* aa = anchors + (size_t)idx * 4;
            float a0 = aa[0], a1 = aa[1], a2 = aa[2], a3 = aa[3];
            float w = a2 - a0, h = a3 - a1;
            float cx = a0 + 0.5f * w, cy = a1 + 0.5f * h;
            float dx = dd[0], dy = dd[1];
            float dw = fminf(dd[2], BBOX_CLIP), dh = fminf(dd[3], BBOX_CLIP);
            float pcx = dx * w + cx, pcy = dy * h + cy;
            float pw = expf(dw) * w, ph = expf(dh) * h;
            float bx1 = pcx - 0.5f * pw, by1 = pcy - 0.5f * ph;
            float bx2 = pcx + 0.5f * pw, by2 = pcy + 0.5f * ph;
            x1 = fminf(fmaxf(bx1, 0.f), IMGSZ);
            y1 = fminf(fmaxf(by1, 0.f), IMGSZ);
            x2 = fminf(fmaxf(bx2, 0.f), IMGSZ);
            y2 = fminf(fmaxf(by2, 0.f), IMGSZ);
            float wsz = x2 - x1, hsz = y2 - y1;
            if (wsz >= MINSZ && hsz >= MINSZ) scv = 1.0f / (1.0f + expf(-o));
        }
    }
    cx1[g] = x1; cy1[g] = y1; cx2[g] = x2; cy2[g] = y2; csc[g] = scv;
}

// ---------------- per-(image,level) greedy NMS: accept + kill ----------------
__global__ __launch_bounds__(256) void nms_kernel(
    const float* __restrict__ cx1, const float* __restrict__ cy1,
    const float* __restrict__ cx2, const float* __restrict__ cy2,
    const float* __restrict__ csc,
    float* __restrict__ svbox, float* __restrict__ svsc, int* __restrict__ svcnt) {
    __shared__ float sx1[CAP], sy1[CAP], sx2[CAP], sy2[CAP], ssc[CAP];
    __shared__ unsigned short survL[CAP];
    __shared__ int wmin[4];

    const int p = blockIdx.x, tid = threadIdx.x;
    const int base = p * CAP;
    for (int i = tid; i < CAP; i += 256) {
        sx1[i] = cx1[base + i]; sy1[i] = cy1[base + i];
        sx2[i] = cx2[base + i]; sy2[i] = cy2[base + i];
        ssc[i] = csc[base + i];
    }
    __syncthreads();

    float bx1[4], by1[4], bx2[4], by2[4];
    unsigned alive = 0;
#pragma unroll
    for (int s = 0; s < 4; ++s) {
        int r = tid * 4 + s;
        bx1[s] = sx1[r]; by1[s] = sy1[r]; bx2[s] = sx2[r]; by2[s] = sy2[r];
        if (ssc[r] > 0.f) alive |= (1u << s);
    }
    const int lane = tid & 63, wid = tid >> 6;
    int nS = 0;

    while (true) {
        unsigned long long ball = __ballot(alive != 0);
        int wj = 0x7FFFFFFF;
        if (ball) {
            int lead = __ffsll((unsigned long long)ball) - 1;
            int myfirst = alive ? (__ffs(alive) - 1) : 0;
            int slot = __shfl(myfirst, lead);
            wj = ((wid << 6) + lead) * 4 + slot;
        }
        if (lane == 0) wmin[wid] = wj;
        __syncthreads();
        int j = min(min(wmin[0], wmin[1]), min(wmin[2], wmin[3]));
        if (j == 0x7FFFFFFF) break;
        if (tid == 0) survL[nS] = (unsigned short)j;
        nS++;
        if (tid == (j >> 2)) alive &= ~(1u << (j & 3));
        float jx1 = sx1[j], jy1 = sy1[j], jx2 = sx2[j], jy2 = sy2[j];
        float jarea = (jx2 - jx1) * (jy2 - jy1);
#pragma unroll
        for (int s = 0; s < 4; ++s) {
            if (alive & (1u << s)) {
                float ltx = fmaxf(jx1, bx1[s]), lty = fmaxf(jy1, by1[s]);
                float rbx = fminf(jx2, bx2[s]), rby = fminf(jy2, by2[s]);
                float wx = fmaxf(rbx - ltx, 0.f), wy = fmaxf(rby - lty, 0.f);
                float inter = wx * wy;
                float ba = (bx2[s] - bx1[s]) * (by2[s] - by1[s]);
                float iou = inter / (jarea + ba - inter);
                if (iou > NMS_TH) alive &= ~(1u << s);
            }
        }
        __syncthreads();
    }

    for (int i = tid; i < nS; i += 256) {
        int r = survL[i];
        int o = base + i;
        svsc[o] = ssc[r];
        svbox[(size_t)o * 4 + 0] = sx1[r];
        svbox[(size_t)o * 4 + 1] = sy1[r];
        svbox[(size_t)o * 4 + 2] = sx2[r];
        svbox[(size_t)o * 4 + 3] = sy2[r];
    }
    if (tid == 0) svcnt[p] = nS;
}

// ---------------- merge 5 survivor lists per image by score (ties -> lower level) ----------------
__global__ __launch_bounds__(256) void merge_kernel(
    const float* __restrict__ svbox, const float* __restrict__ svsc,
    const int* __restrict__ svcnt, float* __restrict__ out) {
    __shared__ float sls[NLVL][CAP];
    __shared__ int scnt[NLVL];
    const int img = blockIdx.x, tid = threadIdx.x;
    if (tid < NLVL) scnt[tid] = svcnt[img * NLVL + tid];
    __syncthreads();
    for (int l = 0; l < NLVL; ++l) {
        int c = scnt[l];
        for (int i = tid; i < c; i += 256) sls[l][i] = svsc[(img * NLVL + l) * CAP + i];
    }
    __syncthreads();
    for (int l = 0; l < NLVL; ++l) {
        int c = scnt[l];
        for (int i = tid; i < c; i += 256) {
            float s = sls[l][i];
            int pos = i;
            for (int m = 0; m < NLVL; ++m) {
                if (m == l) continue;
                int n2 = scnt[m];
                int lo = 0, hi = n2;
                if (m < l) {
                    while (lo < hi) { int mid = (lo + hi) >> 1; if (sls[m][mid] >= s) lo = mid + 1; else hi = mid; }
                } else {
                    while (lo < hi) { int mid = (lo + hi) >> 1; if (sls[m][mid] > s)  lo = mid + 1; else hi = mid; }
                }
                pos += lo;
            }
            if (pos < POST_N) {
                int src = (img * NLVL + l) * CAP + i;
                float* o = out + ((size_t)img * POST_N + pos) * 5;
                o[0] = svbox[(size_t)src * 4 + 0];
                o[1] = svbox[(size_t)src * 4 + 1];
                o[2] = svbox[(size_t)src * 4 + 2];
                o[3] = svbox[(size_t)src * 4 + 3];
                o[4] = s;
            }
        }
    }
}

extern "C" void kernel_launch(void* const* d_in, const int* in_sizes, int n_in,
                              void* d_out, int out_size, void* d_ws, size_t ws_size,
                              hipStream_t stream) {
    const float* obj     = (const float*)d_in[0];
    const float* deltas  = (const float*)d_in[1];
    const float* anchors = (const float*)d_in[2];
    float* out = (float*)d_out;

    char* w = (char*)d_ws;
    size_t off = 0;
    auto alloc = [&](size_t bytes) -> void* {
        void* pp = w + off;
        off += (bytes + 511) & ~(size_t)511;
        return pp;
    };
    unsigned* ghist = (unsigned*)alloc((size_t)NPROB * HBINS * 4);
    unsigned* b1buf = (unsigned*)alloc((size_t)NPROB * 4);
    int*      ccnt  = (int*)alloc((size_t)NPROB * 4);
    unsigned long long* cand = (unsigned long long*)alloc((size_t)NPROB * CCAP * 8);
    unsigned* sel = (unsigned*)alloc((size_t)NPROB * CAP * 4);
    float* cx1 = (float*)alloc((size_t)NPROB * CAP * 4);
    float* cy1 = (float*)alloc((size_t)NPROB * CAP * 4);
    float* cx2 = (float*)alloc((size_t)NPROB * CAP * 4);
    float* cy2 = (float*)alloc((size_t)NPROB * CAP * 4);
    float* csc = (float*)alloc((size_t)NPROB * CAP * 4);
    float* svbox = (float*)alloc((size_t)NPROB * CAP * 16);
    float* svsc  = (float*)alloc((size_t)NPROB * CAP * 4);
    int*   svcnt = (int*)alloc((size_t)NPROB * 4);
    if (off > ws_size) return;  // fail cleanly (output stays poisoned -> visible failure)

    hipMemsetAsync(ghist, 0, (size_t)NPROB * HBINS * 4, stream);
    hipMemsetAsync(ccnt, 0, (size_t)NPROB * 4, stream);
    hipMemsetAsync(d_out, 0, (size_t)out_size * sizeof(float), stream);

    hist_kernel<<<NBATCH * NCHUNK, 256, 0, stream>>>(obj, ghist);
    pick1_kernel<<<NPROB, 256, 0, stream>>>(ghist, b1buf);
    compact_kernel<<<NBATCH * NCHUNK, 256, 0, stream>>>(obj, b1buf, ccnt, cand);
    finalize_kernel<<<NPROB, 256, 0, stream>>>(cand, ccnt, sel);
    decode_kernel<<<(NPROB * CAP) / 256, 256, 0, stream>>>(obj, deltas, anchors, sel,
                                                           cx1, cy1, cx2, cy2, csc);
    nms_kernel<<<NPROB, 256, 0, stream>>>(cx1, cy1, cx2, cy2, csc, svbox, svsc, svcnt);
    merge_kernel<<<NBATCH, 256, 0, stream>>>(svbox, svsc, svcnt, out);
}

// Round 3
// 457.491 us; speedup vs baseline: 2.9340x; 1.6660x over previous
//
#include <hip/hip_runtime.h>
#include <math.h>

#pragma clang fp contract(off)

#define NLVL 5
#define TOTALN 261888
#define NBATCH 16
#define CAP 1024
#define NPROB (NBATCH * NLVL)
#define POST_N 1000
#define NMS_TH 0.7f
#define MINSZ 1e-3f
#define IMGSZ 1024.0f
#define BBOX_CLIP 4.135166556742356f

#define HBINS 2048
#define CCAP 4096
#define NCHUNK 256   // ceil(261888/1024); level offsets are all multiples of 1024

__constant__ int c_loff[NLVL] = {0, 196608, 245760, 258048, 261120};
__constant__ int c_num[NLVL]  = {196608, 49152, 12288, 3072, 768};
__constant__ int c_k[NLVL]    = {1000, 1000, 1000, 1000, 768};

__device__ __forceinline__ unsigned monokey(float f) {
    unsigned b = __float_as_uint(f);
    return (b & 0x80000000u) ? ~b : (b | 0x80000000u);
}

__device__ __forceinline__ int lvl_of_start(int start) {
    return (start >= 261120) ? 4 : (start >= 258048) ? 3 : (start >= 245760) ? 2
         : (start >= 196608) ? 1 : 0;
}

// ---------------- pass 1: per-chunk LDS histogram of top-11 key bits ----------------
__global__ __launch_bounds__(256) void hist_kernel(const float* __restrict__ obj_all,
                                                   unsigned* __restrict__ ghist) {
    __shared__ unsigned lh[HBINS];
    const int tid = threadIdx.x;
    const int chunk = blockIdx.x;
    const int img = chunk >> 8, c = chunk & 255;
    const int start = c << 10;
    const int lvl = lvl_of_start(start);
    const int nrem = min(1024, TOTALN - start);
    for (int i = tid; i < HBINS; i += 256) lh[i] = 0;
    __syncthreads();
    const float* o = obj_all + (size_t)img * TOTALN + start;
    for (int i = tid; i < nrem; i += 256) atomicAdd(&lh[monokey(o[i]) >> 21], 1u);
    __syncthreads();
    unsigned* gh = ghist + (size_t)(img * NLVL + lvl) * HBINS;
    for (int i = tid; i < HBINS; i += 256) {
        unsigned v = lh[i];
        if (v) atomicAdd(&gh[i], v);
    }
}

// ---------------- pick threshold bucket b1 per problem (suffix-sum of hist) ----------------
__global__ __launch_bounds__(256) void pick1_kernel(const unsigned* __restrict__ ghist,
                                                    unsigned* __restrict__ b1out) {
    __shared__ unsigned suf[HBINS];
    const int p = blockIdx.x, tid = threadIdx.x;
    const int k = c_k[p % NLVL];
    const unsigned* gh = ghist + (size_t)p * HBINS;
    for (int i = tid; i < HBINS; i += 256) suf[i] = gh[i];
    __syncthreads();
    for (int d = 1; d < HBINS; d <<= 1) {
        unsigned v[HBINS / 256];
#pragma unroll
        for (int r = 0; r < HBINS / 256; ++r) {
            int i = tid + r * 256;
            v[r] = suf[i] + ((i + d < HBINS) ? suf[i + d] : 0u);
        }
        __syncthreads();
#pragma unroll
        for (int r = 0; r < HBINS / 256; ++r) suf[tid + r * 256] = v[r];
        __syncthreads();
    }
#pragma unroll
    for (int r = 0; r < HBINS / 256; ++r) {
        int i = tid + r * 256;
        if (suf[i] >= (unsigned)k && (i == HBINS - 1 || suf[i + 1] < (unsigned)k))
            b1out[p] = (unsigned)i;
    }
}

// ---------------- pass 2: compact all keys >= (b1<<21) ----------------
__global__ __launch_bounds__(256) void compact_kernel(const float* __restrict__ obj_all,
                                                      const unsigned* __restrict__ b1in,
                                                      int* __restrict__ cnt,
                                                      unsigned long long* __restrict__ cand) {
    __shared__ unsigned long long lkey[1024];
    __shared__ int s_lc, s_base;
    const int tid = threadIdx.x;
    const int chunk = blockIdx.x;
    const int img = chunk >> 8, c = chunk & 255;
    const int start = c << 10;
    const int lvl = lvl_of_start(start);
    const int nrem = min(1024, TOTALN - start);
    const int p = img * NLVL + lvl;
    const unsigned thr = b1in[p] << 21;
    const int local0 = start - c_loff[lvl];
    if (tid == 0) s_lc = 0;
    __syncthreads();
    const float* o = obj_all + (size_t)img * TOTALN + start;
    for (int i = tid; i < nrem; i += 256) {
        unsigned key = monokey(o[i]);
        if (key >= thr) {
            int l = atomicAdd(&s_lc, 1);
            lkey[l] = (((unsigned long long)key) << 32) | (unsigned)(~(unsigned)(local0 + i));
        }
    }
    __syncthreads();
    if (tid == 0) s_base = atomicAdd(&cnt[p], s_lc);
    __syncthreads();
    const int lc = s_lc, base = s_base;
    unsigned long long* cd = cand + (size_t)p * CCAP;
    for (int i = tid; i < lc; i += 256) {
        int pos = base + i;
        if (pos < CCAP) cd[pos] = lkey[i];
    }
}

// ---------------- finalize: sort candidates, emit exact top-k indices ----------------
__global__ __launch_bounds__(256) void finalize_kernel(const unsigned long long* __restrict__ cand,
                                                       const int* __restrict__ cnt,
                                                       unsigned* __restrict__ sel) {
    __shared__ unsigned long long skey[CCAP];
    const int p = blockIdx.x, tid = threadIdx.x;
    const int lvl = p % NLVL, k = c_k[lvl];
    int n = cnt[p]; if (n > CCAP) n = CCAP;
    const unsigned long long* cd = cand + (size_t)p * CCAP;
    for (int i = tid; i < CCAP; i += 256) skey[i] = (i < n) ? cd[i] : 0ull;
    __syncthreads();
    for (int kk = 2; kk <= CCAP; kk <<= 1) {
        for (int j = kk >> 1; j > 0; j >>= 1) {
            for (int i = tid; i < CCAP; i += 256) {
                int ixj = i ^ j;
                if (ixj > i) {
                    unsigned long long a = skey[i], b = skey[ixj];
                    bool up = ((i & kk) != 0);
                    if ((a > b) == up) { skey[i] = b; skey[ixj] = a; }
                }
            }
            __syncthreads();
        }
    }
    const int base = p * CAP;
    for (int r = tid; r < k; r += 256) {
        unsigned li = ~(unsigned)(skey[r] & 0xFFFFFFFFull);
        sel[base + r] = (unsigned)c_loff[lvl] + li;
    }
}

// ---------------- decode + clip + validity + sigmoid ----------------
__global__ __launch_bounds__(256) void decode_kernel(
    const float* __restrict__ obj_all, const float* __restrict__ deltas,
    const float* __restrict__ anchors, const unsigned* __restrict__ sel,
    float* __restrict__ cx1, float* __restrict__ cy1,
    float* __restrict__ cx2, float* __restrict__ cy2, float* __restrict__ csc) {
    int g = blockIdx.x * 256 + threadIdx.x;
    if (g >= NPROB * CAP) return;
    int p = g >> 10, r = g & (CAP - 1);
    int img = p / NLVL, lvl = p % NLVL;
    int k = c_k[lvl];
    float x1 = 0.f, y1 = 0.f, x2 = 0.f, y2 = 0.f, scv = -1.0f;
    if (r < k) {
        unsigned idx = sel[p * CAP + r];
        if (idx < (unsigned)TOTALN) {
            float o = obj_all[(size_t)img * TOTALN + idx];
            const float* dd = deltas + ((size_t)img * TOTALN + (size_t)idx) * 4;
            const float* aa = anchors + (size_t)idx * 4;
            float a0 = aa[0], a1 = aa[1], a2 = aa[2], a3 = aa[3];
            float w = a2 - a0, h = a3 - a1;
            float cx = a0 + 0.5f * w, cy = a1 + 0.5f * h;
            float dx = dd[0], dy = dd[1];
            float dw = fminf(dd[2], BBOX_CLIP), dh = fminf(dd[3], BBOX_CLIP);
            float pcx = dx * w + cx, pcy = dy * h + cy;
            float pw = expf(dw) * w, ph = expf(dh) * h;
            float bx1 = pcx - 0.5f * pw, by1 = pcy - 0.5f * ph;
            float bx2 = pcx + 0.5f * pw, by2 = pcy + 0.5f * ph;
            x1 = fminf(fmaxf(bx1, 0.f), IMGSZ);
            y1 = fminf(fmaxf(by1, 0.f), IMGSZ);
            x2 = fminf(fmaxf(bx2, 0.f), IMGSZ);
            y2 = fminf(fmaxf(by2, 0.f), IMGSZ);
            float wsz = x2 - x1, hsz = y2 - y1;
            if (wsz >= MINSZ && hsz >= MINSZ) scv = 1.0f / (1.0f + expf(-o));
        }
    }
    cx1[g] = x1; cy1[g] = y1; cx2[g] = x2; cy2[g] = y2; csc[g] = scv;
}

// ---------------- NMS phase 1: pairwise suppression-bit matrix ----------------
// mask[(p*CAP+i)*16 + w] : bit jj set iff IoU(i, 64w+jj) > TH and (64w+jj) > i.
// Sub-diagonal words (w < i/64) are left unwritten: bit j of row i is only read
// at scan step j, and row i is only OR'd at step i > j -> garbage is never read.
__global__ __launch_bounds__(256) void mask_kernel(
    const float* __restrict__ cx1, const float* __restrict__ cy1,
    const float* __restrict__ cx2, const float* __restrict__ cy2,
    unsigned long long* __restrict__ mask) {
    __shared__ float sx1[CAP], sy1[CAP], sx2[CAP], sy2[CAP], sar[CAP];
    const int p = blockIdx.x >> 2, rg = blockIdx.x & 3;
    const int tid = threadIdx.x;
    const int base = p * CAP;
    for (int i = tid; i < CAP; i += 256) {
        float a = cx1[base + i], b = cy1[base + i];
        float c = cx2[base + i], d = cy2[base + i];
        sx1[i] = a; sy1[i] = b; sx2[i] = c; sy2[i] = d;
        sar[i] = (c - a) * (d - b);
    }
    __syncthreads();
    const int i = (rg << 8) + tid;
    const float ix1 = sx1[i], iy1 = sy1[i], ix2 = sx2[i], iy2 = sy2[i], iar = sar[i];
    unsigned long long* mr = mask + ((size_t)(base + i) << 4);
    // all 64 lanes of a wave share i>>6, so this loop is wave-uniform
    for (int w = i >> 6; w < 16; ++w) {
        unsigned long long bits = 0;
        const int j0 = w << 6;
        for (int jj = 0; jj < 64; ++jj) {
            const int j = j0 + jj;
            float ltx = fmaxf(ix1, sx1[j]), lty = fmaxf(iy1, sy1[j]);
            float rbx = fminf(ix2, sx2[j]), rby = fminf(iy2, sy2[j]);
            float wx = fmaxf(rbx - ltx, 0.f), wy = fmaxf(rby - lty, 0.f);
            float inter = wx * wy;
            float iou = inter / ((iar + sar[j]) - inter);
            if (iou > NMS_TH && j > i) bits |= (1ull << jj);
        }
        mr[w] = bits;
    }
}

// ---------------- NMS phase 2: serial bit-scan, one wave per problem ----------------
__global__ __launch_bounds__(64) void scan_kernel(
    const unsigned long long* __restrict__ mask,
    const float* __restrict__ cx1, const float* __restrict__ cy1,
    const float* __restrict__ cx2, const float* __restrict__ cy2,
    const float* __restrict__ csc,
    float* __restrict__ svbox, float* __restrict__ svsc, int* __restrict__ svcnt) {
    __shared__ unsigned short survL[CAP];
    const int p = blockIdx.x, lane = threadIdx.x;
    const int base = p * CAP;

    unsigned long long rem = 0;   // lane l (<16) owns suppression bits j in [64l, 64l+64)
    if (lane < 16) {
        const float* sc = csc + base + (lane << 6);
        for (int b = 0; b < 64; ++b)
            if (sc[b] <= 0.f) rem |= (1ull << b);
    }

    const unsigned long long* mrow = mask + ((size_t)base << 4);
    const int wsel = lane & 15;
    unsigned long long pre[8];
#pragma unroll
    for (int r = 0; r < 8; ++r) pre[r] = mrow[(r << 4) + wsel];

    int ns = 0;
    for (int g = 0; g < 128; ++g) {
        unsigned long long cur[8];
#pragma unroll
        for (int r = 0; r < 8; ++r) cur[r] = pre[r];
        if (g < 127) {
            const unsigned long long* nx = mrow + ((size_t)(g + 1) << 7);
#pragma unroll
            for (int r = 0; r < 8; ++r) pre[r] = nx[(r << 4) + wsel];
        }
#pragma unroll
        for (int r = 0; r < 8; ++r) {
            const int i = (g << 3) + r;
            const int w = i >> 6, b = i & 63;
            bool hit = (lane == w) && (((rem >> b) & 1ull) != 0ull);
            if (__ballot(hit) == 0ull) {     // box i alive -> accept
                rem |= cur[r];
                if (lane == 0) survL[ns] = (unsigned short)i;
                ++ns;
            }
        }
    }
    __syncthreads();
    for (int s = lane; s < ns; s += 64) {
        int r = survL[s];
        int o = base + s;
        svsc[o] = csc[base + r];
        svbox[(size_t)o * 4 + 0] = cx1[base + r];
        svbox[(size_t)o * 4 + 1] = cy1[base + r];
        svbox[(size_t)o * 4 + 2] = cx2[base + r];
        svbox[(size_t)o * 4 + 3] = cy2[base + r];
    }
    if (lane == 0) svcnt[p] = ns;
}

// ---------------- merge 5 survivor lists per image by score (ties -> lower level) ----------------
__global__ __launch_bounds__(256) void merge_kernel(
    const float* __restrict__ svbox, const float* __restrict__ svsc,
    const int* __restrict__ svcnt, float* __restrict__ out) {
    __shared__ float sls[NLVL][CAP];
    __shared__ int scnt[NLVL];
    const int img = blockIdx.x, tid = threadIdx.x;
    if (tid < NLVL) scnt[tid] = svcnt[img * NLVL + tid];
    __syncthreads();
    for (int l = 0; l < NLVL; ++l) {
        int c = scnt[l];
        for (int i = tid; i < c; i += 256) sls[l][i] = svsc[(img * NLVL + l) * CAP + i];
    }
    __syncthreads();
    for (int l = 0; l < NLVL; ++l) {
        int c = scnt[l];
        for (int i = tid; i < c; i += 256) {
            float s = sls[l][i];
            int pos = i;
            for (int m = 0; m < NLVL; ++m) {
                if (m == l) continue;
                int n2 = scnt[m];
                int lo = 0, hi = n2;
                if (m < l) {
                    while (lo < hi) { int mid = (lo + hi) >> 1; if (sls[m][mid] >= s) lo = mid + 1; else hi = mid; }
                } else {
                    while (lo < hi) { int mid = (lo + hi) >> 1; if (sls[m][mid] > s)  lo = mid + 1; else hi = mid; }
                }
                pos += lo;
            }
            if (pos < POST_N) {
                int src = (img * NLVL + l) * CAP + i;
                float* o = out + ((size_t)img * POST_N + pos) * 5;
                o[0] = svbox[(size_t)src * 4 + 0];
                o[1] = svbox[(size_t)src * 4 + 1];
                o[2] = svbox[(size_t)src * 4 + 2];
                o[3] = svbox[(size_t)src * 4 + 3];
                o[4] = s;
            }
        }
    }
}

extern "C" void kernel_launch(void* const* d_in, const int* in_sizes, int n_in,
                              void* d_out, int out_size, void* d_ws, size_t ws_size,
                              hipStream_t stream) {
    const float* obj     = (const float*)d_in[0];
    const float* deltas  = (const float*)d_in[1];
    const float* anchors = (const float*)d_in[2];
    float* out = (float*)d_out;

    char* w = (char*)d_ws;
    size_t off = 0;
    auto alloc = [&](size_t bytes) -> void* {
        void* pp = w + off;
        off += (bytes + 511) & ~(size_t)511;
        return pp;
    };
    unsigned* ghist = (unsigned*)alloc((size_t)NPROB * HBINS * 4);
    unsigned* b1buf = (unsigned*)alloc((size_t)NPROB * 4);
    int*      ccnt  = (int*)alloc((size_t)NPROB * 4);
    unsigned long long* cand = (unsigned long long*)alloc((size_t)NPROB * CCAP * 8);
    unsigned* sel = (unsigned*)alloc((size_t)NPROB * CAP * 4);
    float* cx1 = (float*)alloc((size_t)NPROB * CAP * 4);
    float* cy1 = (float*)alloc((size_t)NPROB * CAP * 4);
    float* cx2 = (float*)alloc((size_t)NPROB * CAP * 4);
    float* cy2 = (float*)alloc((size_t)NPROB * CAP * 4);
    float* csc = (float*)alloc((size_t)NPROB * CAP * 4);
    float* svbox = (float*)alloc((size_t)NPROB * CAP * 16);
    float* svsc  = (float*)alloc((size_t)NPROB * CAP * 4);
    int*   svcnt = (int*)alloc((size_t)NPROB * 4);
    unsigned long long* nmask = (unsigned long long*)alloc((size_t)NPROB * CAP * 16 * 8);
    if (off > ws_size) return;  // fail cleanly (output stays poisoned -> visible failure)

    hipMemsetAsync(ghist, 0, (size_t)NPROB * HBINS * 4, stream);
    hipMemsetAsync(ccnt, 0, (size_t)NPROB * 4, stream);
    hipMemsetAsync(d_out, 0, (size_t)out_size * sizeof(float), stream);

    hist_kernel<<<NBATCH * NCHUNK, 256, 0, stream>>>(obj, ghist);
    pick1_kernel<<<NPROB, 256, 0, stream>>>(ghist, b1buf);
    compact_kernel<<<NBATCH * NCHUNK, 256, 0, stream>>>(obj, b1buf, ccnt, cand);
    finalize_kernel<<<NPROB, 256, 0, stream>>>(cand, ccnt, sel);
    decode_kernel<<<(NPROB * CAP) / 256, 256, 0, stream>>>(obj, deltas, anchors, sel,
                                                           cx1, cy1, cx2, cy2, csc);
    mask_kernel<<<NPROB * 4, 256, 0, stream>>>(cx1, cy1, cx2, cy2, nmask);
    scan_kernel<<<NPROB, 64, 0, stream>>>(nmask, cx1, cy1, cx2, cy2, csc, svbox, svsc, svcnt);
    merge_kernel<<<NBATCH, 256, 0, stream>>>(svbox, svsc, svcnt, out);
}

// Round 4
// 366.145 us; speedup vs baseline: 3.6660x; 1.2495x over previous
//
#include <hip/hip_runtime.h>
#include <math.h>

#pragma clang fp contract(off)

#define NLVL 5
#define TOTALN 261888
#define NBATCH 16
#define CAP 1024
#define NPROB (NBATCH * NLVL)
#define POST_N 1000
#define NMS_TH 0.7f
#define MINSZ 1e-3f
#define IMGSZ 1024.0f
#define BBOX_CLIP 4.135166556742356f

#define HBINS 2048
#define CCAP 4096
#define NCHUNK 256   // ceil(261888/1024); level offsets are all multiples of 1024

__constant__ int c_loff[NLVL] = {0, 196608, 245760, 258048, 261120};
__constant__ int c_num[NLVL]  = {196608, 49152, 12288, 3072, 768};
__constant__ int c_k[NLVL]    = {1000, 1000, 1000, 1000, 768};

__device__ __forceinline__ unsigned monokey(float f) {
    unsigned b = __float_as_uint(f);
    return (b & 0x80000000u) ? ~b : (b | 0x80000000u);
}

__device__ __forceinline__ int lvl_of_start(int start) {
    return (start >= 261120) ? 4 : (start >= 258048) ? 3 : (start >= 245760) ? 2
         : (start >= 196608) ? 1 : 0;
}

// ---------------- pass 1: per-chunk LDS histogram of top-11 key bits ----------------
__global__ __launch_bounds__(256) void hist_kernel(const float* __restrict__ obj_all,
                                                   unsigned* __restrict__ ghist) {
    __shared__ unsigned lh[HBINS];
    const int tid = threadIdx.x;
    const int chunk = blockIdx.x;
    const int img = chunk >> 8, c = chunk & 255;
    const int start = c << 10;
    const int lvl = lvl_of_start(start);
    const int nrem = min(1024, TOTALN - start);
    for (int i = tid; i < HBINS; i += 256) lh[i] = 0;
    __syncthreads();
    const float* o = obj_all + (size_t)img * TOTALN + start;
    for (int i = tid; i < nrem; i += 256) atomicAdd(&lh[monokey(o[i]) >> 21], 1u);
    __syncthreads();
    unsigned* gh = ghist + (size_t)(img * NLVL + lvl) * HBINS;
    for (int i = tid; i < HBINS; i += 256) {
        unsigned v = lh[i];
        if (v) atomicAdd(&gh[i], v);
    }
}

// ---------------- pick threshold bucket b1 per problem (suffix-sum of hist) ----------------
__global__ __launch_bounds__(256) void pick1_kernel(const unsigned* __restrict__ ghist,
                                                    unsigned* __restrict__ b1out) {
    __shared__ unsigned suf[HBINS];
    const int p = blockIdx.x, tid = threadIdx.x;
    const int k = c_k[p % NLVL];
    const unsigned* gh = ghist + (size_t)p * HBINS;
    for (int i = tid; i < HBINS; i += 256) suf[i] = gh[i];
    __syncthreads();
    for (int d = 1; d < HBINS; d <<= 1) {
        unsigned v[HBINS / 256];
#pragma unroll
        for (int r = 0; r < HBINS / 256; ++r) {
            int i = tid + r * 256;
            v[r] = suf[i] + ((i + d < HBINS) ? suf[i + d] : 0u);
        }
        __syncthreads();
#pragma unroll
        for (int r = 0; r < HBINS / 256; ++r) suf[tid + r * 256] = v[r];
        __syncthreads();
    }
#pragma unroll
    for (int r = 0; r < HBINS / 256; ++r) {
        int i = tid + r * 256;
        if (suf[i] >= (unsigned)k && (i == HBINS - 1 || suf[i + 1] < (unsigned)k))
            b1out[p] = (unsigned)i;
    }
}

// ---------------- pass 2: compact all keys >= (b1<<21) ----------------
__global__ __launch_bounds__(256) void compact_kernel(const float* __restrict__ obj_all,
                                                      const unsigned* __restrict__ b1in,
                                                      int* __restrict__ cnt,
                                                      unsigned long long* __restrict__ cand) {
    __shared__ unsigned long long lkey[1024];
    __shared__ int s_lc, s_base;
    const int tid = threadIdx.x;
    const int chunk = blockIdx.x;
    const int img = chunk >> 8, c = chunk & 255;
    const int start = c << 10;
    const int lvl = lvl_of_start(start);
    const int nrem = min(1024, TOTALN - start);
    const int p = img * NLVL + lvl;
    const unsigned thr = b1in[p] << 21;
    const int local0 = start - c_loff[lvl];
    if (tid == 0) s_lc = 0;
    __syncthreads();
    const float* o = obj_all + (size_t)img * TOTALN + start;
    for (int i = tid; i < nrem; i += 256) {
        unsigned key = monokey(o[i]);
        if (key >= thr) {
            int l = atomicAdd(&s_lc, 1);
            lkey[l] = (((unsigned long long)key) << 32) | (unsigned)(~(unsigned)(local0 + i));
        }
    }
    __syncthreads();
    if (tid == 0) s_base = atomicAdd(&cnt[p], s_lc);
    __syncthreads();
    const int lc = s_lc, base = s_base;
    unsigned long long* cd = cand + (size_t)p * CCAP;
    for (int i = tid; i < lc; i += 256) {
        int pos = base + i;
        if (pos < CCAP) cd[pos] = lkey[i];
    }
}

// ---------------- finalize via rank: pos_i = #{j : key_j > key_i}, barrier-free ----------------
// Keys are all distinct (original index embedded in low 32 bits), so the rank is an
// exact sort permutation; only ranks < k are emitted. 16 blocks/problem, early-exit.
__global__ __launch_bounds__(256) void rank_kernel(const unsigned long long* __restrict__ cand,
                                                   const int* __restrict__ cnt,
                                                   unsigned* __restrict__ sel) {
    __shared__ unsigned long long skey[CCAP];
    const int p = blockIdx.x >> 4;
    const int blk = blockIdx.x & 15;
    const int tid = threadIdx.x;
    const int lvl = p % NLVL, k = c_k[lvl];
    int n = cnt[p]; if (n > CCAP) n = CCAP;
    const int i0 = blk << 8;
    if (i0 >= n) return;                       // block-uniform exit, no barrier crossed
    const unsigned long long* cd = cand + (size_t)p * CCAP;
    const int n8 = (n + 7) & ~7;
    for (int i = tid; i < n8; i += 256) skey[i] = (i < n) ? cd[i] : 0ull;
    __syncthreads();
    const int i = i0 + tid;
    const unsigned long long my = (i < n) ? skey[i] : ~0ull;  // sentinel -> rank 0, not emitted
    int rank = 0;
    for (int j = 0; j < n8; j += 8) {          // wave-uniform LDS broadcast reads
        unsigned long long k0 = skey[j + 0], k1 = skey[j + 1];
        unsigned long long k2 = skey[j + 2], k3 = skey[j + 3];
        unsigned long long k4 = skey[j + 4], k5 = skey[j + 5];
        unsigned long long k6 = skey[j + 6], k7 = skey[j + 7];
        rank += (int)(k0 > my) + (int)(k1 > my) + (int)(k2 > my) + (int)(k3 > my)
              + (int)(k4 > my) + (int)(k5 > my) + (int)(k6 > my) + (int)(k7 > my);
    }
    if (i < n && rank < k) {
        unsigned li = ~(unsigned)(my & 0xFFFFFFFFull);
        sel[p * CAP + rank] = (unsigned)c_loff[lvl] + li;
    }
}

// ---------------- decode + clip + validity + sigmoid ----------------
__global__ __launch_bounds__(256) void decode_kernel(
    const float* __restrict__ obj_all, const float* __restrict__ deltas,
    const float* __restrict__ anchors, const unsigned* __restrict__ sel,
    float* __restrict__ cx1, float* __restrict__ cy1,
    float* __restrict__ cx2, float* __restrict__ cy2, float* __restrict__ csc) {
    int g = blockIdx.x * 256 + threadIdx.x;
    if (g >= NPROB * CAP) return;
    int p = g >> 10, r = g & (CAP - 1);
    int img = p / NLVL, lvl = p % NLVL;
    int k = c_k[lvl];
    float x1 = 0.f, y1 = 0.f, x2 = 0.f, y2 = 0.f, scv = -1.0f;
    if (r < k) {
        unsigned idx = sel[p * CAP + r];
        if (idx < (unsigned)TOTALN) {
            float o = obj_all[(size_t)img * TOTALN + idx];
            const float* dd = deltas + ((size_t)img * TOTALN + (size_t)idx) * 4;
            const float* aa = anchors + (size_t)idx * 4;
            float a0 = aa[0], a1 = aa[1], a2 = aa[2], a3 = aa[3];
            float w = a2 - a0, h = a3 - a1;
            float cx = a0 + 0.5f * w, cy = a1 + 0.5f * h;
            float dx = dd[0], dy = dd[1];
            float dw = fminf(dd[2], BBOX_CLIP), dh = fminf(dd[3], BBOX_CLIP);
            float pcx = dx * w + cx, pcy = dy * h + cy;
            float pw = expf(dw) * w, ph = expf(dh) * h;
            float bx1 = pcx - 0.5f * pw, by1 = pcy - 0.5f * ph;
            float bx2 = pcx + 0.5f * pw, by2 = pcy + 0.5f * ph;
            x1 = fminf(fmaxf(bx1, 0.f), IMGSZ);
            y1 = fminf(fmaxf(by1, 0.f), IMGSZ);
            x2 = fminf(fmaxf(bx2, 0.f), IMGSZ);
            y2 = fminf(fmaxf(by2, 0.f), IMGSZ);
            float wsz = x2 - x1, hsz = y2 - y1;
            if (wsz >= MINSZ && hsz >= MINSZ) scv = 1.0f / (1.0f + expf(-o));
        }
    }
    cx1[g] = x1; cy1[g] = y1; cx2[g] = x2; cy2[g] = y2; csc[g] = scv;
}

// ---------------- NMS phase 1: pairwise suppression-bit matrix ----------------
// mask[(p*CAP+i)*16 + w] : bit jj set iff IoU(i, 64w+jj) > TH and (64w+jj) > i.
// Sub-diagonal words (w < i/64) are left unwritten: bit j of row i is only read
// at scan step j, and row i is only OR'd at step i > j -> garbage is never read.
__global__ __launch_bounds__(256) void mask_kernel(
    const float* __restrict__ cx1, const float* __restrict__ cy1,
    const float* __restrict__ cx2, const float* __restrict__ cy2,
    unsigned long long* __restrict__ mask) {
    __shared__ float sx1[CAP], sy1[CAP], sx2[CAP], sy2[CAP], sar[CAP];
    const int p = blockIdx.x >> 2, rg = blockIdx.x & 3;
    const int tid = threadIdx.x;
    const int base = p * CAP;
    for (int i = tid; i < CAP; i += 256) {
        float a = cx1[base + i], b = cy1[base + i];
        float c = cx2[base + i], d = cy2[base + i];
        sx1[i] = a; sy1[i] = b; sx2[i] = c; sy2[i] = d;
        sar[i] = (c - a) * (d - b);
    }
    __syncthreads();
    const int i = (rg << 8) + tid;
    const float ix1 = sx1[i], iy1 = sy1[i], ix2 = sx2[i], iy2 = sy2[i], iar = sar[i];
    unsigned long long* mr = mask + ((size_t)(base + i) << 4);
    // all 64 lanes of a wave share i>>6, so this loop is wave-uniform
    for (int w = i >> 6; w < 16; ++w) {
        unsigned long long bits = 0;
        const int j0 = w << 6;
        for (int jj = 0; jj < 64; ++jj) {
            const int j = j0 + jj;
            float ltx = fmaxf(ix1, sx1[j]), lty = fmaxf(iy1, sy1[j]);
            float rbx = fminf(ix2, sx2[j]), rby = fminf(iy2, sy2[j]);
            float wx = fmaxf(rbx - ltx, 0.f), wy = fmaxf(rby - lty, 0.f);
            float inter = wx * wy;
            float iou = inter / ((iar + sar[j]) - inter);
            if (iou > NMS_TH && j > i) bits |= (1ull << jj);
        }
        mr[w] = bits;
    }
}

// ---------------- NMS phase 2: serial bit-scan, one wave per problem ----------------
__global__ __launch_bounds__(64) void scan_kernel(
    const unsigned long long* __restrict__ mask,
    const float* __restrict__ cx1, const float* __restrict__ cy1,
    const float* __restrict__ cx2, const float* __restrict__ cy2,
    const float* __restrict__ csc,
    float* __restrict__ svbox, float* __restrict__ svsc, int* __restrict__ svcnt) {
    __shared__ unsigned short survL[CAP];
    const int p = blockIdx.x, lane = threadIdx.x;
    const int base = p * CAP;

    unsigned long long rem = 0;   // lane l (<16) owns suppression bits j in [64l, 64l+64)
    if (lane < 16) {
        const float* sc = csc + base + (lane << 6);
        for (int b = 0; b < 64; ++b)
            if (sc[b] <= 0.f) rem |= (1ull << b);
    }

    const unsigned long long* mrow = mask + ((size_t)base << 4);
    const int wsel = lane & 15;
    unsigned long long pre[8];
#pragma unroll
    for (int r = 0; r < 8; ++r) pre[r] = mrow[(r << 4) + wsel];

    int ns = 0;
    for (int g = 0; g < 128; ++g) {
        unsigned long long cur[8];
#pragma unroll
        for (int r = 0; r < 8; ++r) cur[r] = pre[r];
        if (g < 127) {
            const unsigned long long* nx = mrow + ((size_t)(g + 1) << 7);
#pragma unroll
            for (int r = 0; r < 8; ++r) pre[r] = nx[(r << 4) + wsel];
        }
#pragma unroll
        for (int r = 0; r < 8; ++r) {
            const int i = (g << 3) + r;
            const int w = i >> 6, b = i & 63;
            bool hit = (lane == w) && (((rem >> b) & 1ull) != 0ull);
            if (__ballot(hit) == 0ull) {     // box i alive -> accept
                rem |= cur[r];
                if (lane == 0) survL[ns] = (unsigned short)i;
                ++ns;
            }
        }
    }
    __syncthreads();
    for (int s = lane; s < ns; s += 64) {
        int r = survL[s];
        int o = base + s;
        svsc[o] = csc[base + r];
        svbox[(size_t)o * 4 + 0] = cx1[base + r];
        svbox[(size_t)o * 4 + 1] = cy1[base + r];
        svbox[(size_t)o * 4 + 2] = cx2[base + r];
        svbox[(size_t)o * 4 + 3] = cy2[base + r];
    }
    if (lane == 0) svcnt[p] = ns;
}

// ---------------- merge 5 survivor lists per image by score (ties -> lower level) ----------------
__global__ __launch_bounds__(256) void merge_kernel(
    const float* __restrict__ svbox, const float* __restrict__ svsc,
    const int* __restrict__ svcnt, float* __restrict__ out) {
    __shared__ float sls[NLVL][CAP];
    __shared__ int scnt[NLVL];
    const int img = blockIdx.x, tid = threadIdx.x;
    if (tid < NLVL) scnt[tid] = svcnt[img * NLVL + tid];
    __syncthreads();
    for (int l = 0; l < NLVL; ++l) {
        int c = scnt[l];
        for (int i = tid; i < c; i += 256) sls[l][i] = svsc[(img * NLVL + l) * CAP + i];
    }
    __syncthreads();
    for (int l = 0; l < NLVL; ++l) {
        int c = scnt[l];
        for (int i = tid; i < c; i += 256) {
            float s = sls[l][i];
            int pos = i;
            for (int m = 0; m < NLVL; ++m) {
                if (m == l) continue;
                int n2 = scnt[m];
                int lo = 0, hi = n2;
                if (m < l) {
                    while (lo < hi) { int mid = (lo + hi) >> 1; if (sls[m][mid] >= s) lo = mid + 1; else hi = mid; }
                } else {
                    while (lo < hi) { int mid = (lo + hi) >> 1; if (sls[m][mid] > s)  lo = mid + 1; else hi = mid; }
                }
                pos += lo;
            }
            if (pos < POST_N) {
                int src = (img * NLVL + l) * CAP + i;
                float* o = out + ((size_t)img * POST_N + pos) * 5;
                o[0] = svbox[(size_t)src * 4 + 0];
                o[1] = svbox[(size_t)src * 4 + 1];
                o[2] = svbox[(size_t)src * 4 + 2];
                o[3] = svbox[(size_t)src * 4 + 3];
                o[4] = s;
            }
        }
    }
}

extern "C" void kernel_launch(void* const* d_in, const int* in_sizes, int n_in,
                              void* d_out, int out_size, void* d_ws, size_t ws_size,
                              hipStream_t stream) {
    const float* obj     = (const float*)d_in[0];
    const float* deltas  = (const float*)d_in[1];
    const float* anchors = (const float*)d_in[2];
    float* out = (float*)d_out;

    char* w = (char*)d_ws;
    size_t off = 0;
    auto alloc = [&](size_t bytes) -> void* {
        void* pp = w + off;
        off += (bytes + 511) & ~(size_t)511;
        return pp;
    };
    unsigned* ghist = (unsigned*)alloc((size_t)NPROB * HBINS * 4);
    unsigned* b1buf = (unsigned*)alloc((size_t)NPROB * 4);
    int*      ccnt  = (int*)alloc((size_t)NPROB * 4);
    unsigned long long* cand = (unsigned long long*)alloc((size_t)NPROB * CCAP * 8);
    unsigned* sel = (unsigned*)alloc((size_t)NPROB * CAP * 4);
    float* cx1 = (float*)alloc((size_t)NPROB * CAP * 4);
    float* cy1 = (float*)alloc((size_t)NPROB * CAP * 4);
    float* cx2 = (float*)alloc((size_t)NPROB * CAP * 4);
    float* cy2 = (float*)alloc((size_t)NPROB * CAP * 4);
    float* csc = (float*)alloc((size_t)NPROB * CAP * 4);
    float* svbox = (float*)alloc((size_t)NPROB * CAP * 16);
    float* svsc  = (float*)alloc((size_t)NPROB * CAP * 4);
    int*   svcnt = (int*)alloc((size_t)NPROB * 4);
    unsigned long long* nmask = (unsigned long long*)alloc((size_t)NPROB * CAP * 16 * 8);
    if (off > ws_size) return;  // fail cleanly (output stays poisoned -> visible failure)

    hipMemsetAsync(ghist, 0, (size_t)NPROB * HBINS * 4, stream);
    hipMemsetAsync(ccnt, 0, (size_t)NPROB * 4, stream);
    hipMemsetAsync(d_out, 0, (size_t)out_size * sizeof(float), stream);

    hist_kernel<<<NBATCH * NCHUNK, 256, 0, stream>>>(obj, ghist);
    pick1_kernel<<<NPROB, 256, 0, stream>>>(ghist, b1buf);
    compact_kernel<<<NBATCH * NCHUNK, 256, 0, stream>>>(obj, b1buf, ccnt, cand);
    rank_kernel<<<NPROB * 16, 256, 0, stream>>>(cand, ccnt, sel);
    decode_kernel<<<(NPROB * CAP) / 256, 256, 0, stream>>>(obj, deltas, anchors, sel,
                                                           cx1, cy1, cx2, cy2, csc);
    mask_kernel<<<NPROB * 4, 256, 0, stream>>>(cx1, cy1, cx2, cy2, nmask);
    scan_kernel<<<NPROB, 64, 0, stream>>>(nmask, cx1, cy1, cx2, cy2, csc, svbox, svsc, svcnt);
    merge_kernel<<<NBATCH, 256, 0, stream>>>(svbox, svsc, svcnt, out);
}

// Round 5
// 293.493 us; speedup vs baseline: 4.5735x; 1.2475x over previous
//
#include <hip/hip_runtime.h>
#include <math.h>

#pragma clang fp contract(off)

#define NLVL 5
#define TOTALN 261888
#define NBATCH 16
#define CAP 1024
#define NPROB (NBATCH * NLVL)
#define POST_N 1000
#define NMS_TH 0.7f
#define MINSZ 1e-3f
#define IMGSZ 1024.0f
#define BBOX_CLIP 4.135166556742356f

#define HBINS 2048
#define CCAP 4096
#define NCHUNK 256   // ceil(261888/1024); level offsets are all multiples of 1024

__constant__ int c_loff[NLVL] = {0, 196608, 245760, 258048, 261120};
__constant__ int c_num[NLVL]  = {196608, 49152, 12288, 3072, 768};
__constant__ int c_k[NLVL]    = {1000, 1000, 1000, 1000, 768};

// (rg, wg) tile list for the upper-triangular mask: wg >= rg
__constant__ int c_rg[10] = {0,0,0,0,1,1,1,2,2,3};
__constant__ int c_wg[10] = {0,1,2,3,1,2,3,2,3,3};

__device__ __forceinline__ unsigned monokey(float f) {
    unsigned b = __float_as_uint(f);
    return (b & 0x80000000u) ? ~b : (b | 0x80000000u);
}

__device__ __forceinline__ int lvl_of_start(int start) {
    return (start >= 261120) ? 4 : (start >= 258048) ? 3 : (start >= 245760) ? 2
         : (start >= 196608) ? 1 : 0;
}

// ---------------- pass 1: per-chunk LDS histogram of top-11 key bits ----------------
__global__ __launch_bounds__(256) void hist_kernel(const float* __restrict__ obj_all,
                                                   unsigned* __restrict__ ghist) {
    __shared__ unsigned lh[HBINS];
    const int tid = threadIdx.x;
    const int chunk = blockIdx.x;
    const int img = chunk >> 8, c = chunk & 255;
    const int start = c << 10;
    const int lvl = lvl_of_start(start);
    const int nrem = min(1024, TOTALN - start);
    for (int i = tid; i < HBINS; i += 256) lh[i] = 0;
    __syncthreads();
    const float* o = obj_all + (size_t)img * TOTALN + start;
    for (int i = tid; i < nrem; i += 256) atomicAdd(&lh[monokey(o[i]) >> 21], 1u);
    __syncthreads();
    unsigned* gh = ghist + (size_t)(img * NLVL + lvl) * HBINS;
    for (int i = tid; i < HBINS; i += 256) {
        unsigned v = lh[i];
        if (v) atomicAdd(&gh[i], v);
    }
}

// ---------------- pick threshold bucket b1 per problem (suffix-sum of hist) ----------------
__global__ __launch_bounds__(256) void pick1_kernel(const unsigned* __restrict__ ghist,
                                                    unsigned* __restrict__ b1out) {
    __shared__ unsigned suf[HBINS];
    const int p = blockIdx.x, tid = threadIdx.x;
    const int k = c_k[p % NLVL];
    const unsigned* gh = ghist + (size_t)p * HBINS;
    for (int i = tid; i < HBINS; i += 256) suf[i] = gh[i];
    __syncthreads();
    for (int d = 1; d < HBINS; d <<= 1) {
        unsigned v[HBINS / 256];
#pragma unroll
        for (int r = 0; r < HBINS / 256; ++r) {
            int i = tid + r * 256;
            v[r] = suf[i] + ((i + d < HBINS) ? suf[i + d] : 0u);
        }
        __syncthreads();
#pragma unroll
        for (int r = 0; r < HBINS / 256; ++r) suf[tid + r * 256] = v[r];
        __syncthreads();
    }
#pragma unroll
    for (int r = 0; r < HBINS / 256; ++r) {
        int i = tid + r * 256;
        if (suf[i] >= (unsigned)k && (i == HBINS - 1 || suf[i + 1] < (unsigned)k))
            b1out[p] = (unsigned)i;
    }
}

// ---------------- pass 2: compact all keys >= (b1<<21) ----------------
__global__ __launch_bounds__(256) void compact_kernel(const float* __restrict__ obj_all,
                                                      const unsigned* __restrict__ b1in,
                                                      int* __restrict__ cnt,
                                                      unsigned long long* __restrict__ cand) {
    __shared__ unsigned long long lkey[1024];
    __shared__ int s_lc, s_base;
    const int tid = threadIdx.x;
    const int chunk = blockIdx.x;
    const int img = chunk >> 8, c = chunk & 255;
    const int start = c << 10;
    const int lvl = lvl_of_start(start);
    const int nrem = min(1024, TOTALN - start);
    const int p = img * NLVL + lvl;
    const unsigned thr = b1in[p] << 21;
    const int local0 = start - c_loff[lvl];
    if (tid == 0) s_lc = 0;
    __syncthreads();
    const float* o = obj_all + (size_t)img * TOTALN + start;
    for (int i = tid; i < nrem; i += 256) {
        unsigned key = monokey(o[i]);
        if (key >= thr) {
            int l = atomicAdd(&s_lc, 1);
            lkey[l] = (((unsigned long long)key) << 32) | (unsigned)(~(unsigned)(local0 + i));
        }
    }
    __syncthreads();
    if (tid == 0) s_base = atomicAdd(&cnt[p], s_lc);
    __syncthreads();
    const int lc = s_lc, base = s_base;
    unsigned long long* cd = cand + (size_t)p * CCAP;
    for (int i = tid; i < lc; i += 256) {
        int pos = base + i;
        if (pos < CCAP) cd[pos] = lkey[i];
    }
}

// ---------------- finalize via rank: pos_i = #{j : key_j > key_i}, barrier-free ----------------
__global__ __launch_bounds__(256) void rank_kernel(const unsigned long long* __restrict__ cand,
                                                   const int* __restrict__ cnt,
                                                   unsigned* __restrict__ sel) {
    __shared__ unsigned long long skey[CCAP];
    const int p = blockIdx.x >> 4;
    const int blk = blockIdx.x & 15;
    const int tid = threadIdx.x;
    const int lvl = p % NLVL, k = c_k[lvl];
    int n = cnt[p]; if (n > CCAP) n = CCAP;
    const int i0 = blk << 8;
    if (i0 >= n) return;                       // block-uniform exit, no barrier crossed
    const unsigned long long* cd = cand + (size_t)p * CCAP;
    const int n8 = (n + 7) & ~7;
    for (int i = tid; i < n8; i += 256) skey[i] = (i < n) ? cd[i] : 0ull;
    __syncthreads();
    const int i = i0 + tid;
    const unsigned long long my = (i < n) ? skey[i] : ~0ull;  // sentinel -> rank 0, not emitted
    int rank = 0;
    for (int j = 0; j < n8; j += 8) {          // wave-uniform LDS broadcast reads
        unsigned long long k0 = skey[j + 0], k1 = skey[j + 1];
        unsigned long long k2 = skey[j + 2], k3 = skey[j + 3];
        unsigned long long k4 = skey[j + 4], k5 = skey[j + 5];
        unsigned long long k6 = skey[j + 6], k7 = skey[j + 7];
        rank += (int)(k0 > my) + (int)(k1 > my) + (int)(k2 > my) + (int)(k3 > my)
              + (int)(k4 > my) + (int)(k5 > my) + (int)(k6 > my) + (int)(k7 > my);
    }
    if (i < n && rank < k) {
        unsigned li = ~(unsigned)(my & 0xFFFFFFFFull);
        sel[p * CAP + rank] = (unsigned)c_loff[lvl] + li;
    }
}

// ---------------- decode + clip + validity + sigmoid ----------------
__global__ __launch_bounds__(256) void decode_kernel(
    const float* __restrict__ obj_all, const float* __restrict__ deltas,
    const float* __restrict__ anchors, const unsigned* __restrict__ sel,
    float* __restrict__ cx1, float* __restrict__ cy1,
    float* __restrict__ cx2, float* __restrict__ cy2, float* __restrict__ csc) {
    int g = blockIdx.x * 256 + threadIdx.x;
    if (g >= NPROB * CAP) return;
    int p = g >> 10, r = g & (CAP - 1);
    int img = p / NLVL, lvl = p % NLVL;
    int k = c_k[lvl];
    float x1 = 0.f, y1 = 0.f, x2 = 0.f, y2 = 0.f, scv = -1.0f;
    if (r < k) {
        unsigned idx = sel[p * CAP + r];
        if (idx < (unsigned)TOTALN) {
            float o = obj_all[(size_t)img * TOTALN + idx];
            const float* dd = deltas + ((size_t)img * TOTALN + (size_t)idx) * 4;
            const float* aa = anchors + (size_t)idx * 4;
            float a0 = aa[0], a1 = aa[1], a2 = aa[2], a3 = aa[3];
            float w = a2 - a0, h = a3 - a1;
            float cx = a0 + 0.5f * w, cy = a1 + 0.5f * h;
            float dx = dd[0], dy = dd[1];
            float dw = fminf(dd[2], BBOX_CLIP), dh = fminf(dd[3], BBOX_CLIP);
            float pcx = dx * w + cx, pcy = dy * h + cy;
            float pw = expf(dw) * w, ph = expf(dh) * h;
            float bx1 = pcx - 0.5f * pw, by1 = pcy - 0.5f * ph;
            float bx2 = pcx + 0.5f * pw, by2 = pcy + 0.5f * ph;
            x1 = fminf(fmaxf(bx1, 0.f), IMGSZ);
            y1 = fminf(fmaxf(by1, 0.f), IMGSZ);
            x2 = fminf(fmaxf(bx2, 0.f), IMGSZ);
            y2 = fminf(fmaxf(by2, 0.f), IMGSZ);
            float wsz = x2 - x1, hsz = y2 - y1;
            if (wsz >= MINSZ && hsz >= MINSZ) scv = 1.0f / (1.0f + expf(-o));
        }
    }
    cx1[g] = x1; cy1[g] = y1; cx2[g] = x2; cy2[g] = y2; csc[g] = scv;
}

// ---------------- NMS phase 1: pairwise suppression-bit matrix (tiled) ----------------
// One block per (problem, rg, wg), wg >= rg. Rows [rg*256,+256) x words [wg*4,+4).
// mask[(p*CAP+i)*16 + w] : bit jj set iff IoU(i, 64w+jj) > TH and (64w+jj) > i.
// Sub-diagonal words stay unwritten: bit j of row i is only read at scan step j,
// and row i is only OR'd at step i > j -> garbage is never read.
__global__ __launch_bounds__(256) void mask_kernel(
    const float* __restrict__ cx1, const float* __restrict__ cy1,
    const float* __restrict__ cx2, const float* __restrict__ cy2,
    unsigned long long* __restrict__ mask) {
    __shared__ float sx1[256], sy1[256], sx2[256], sy2[256], sar[256];
    const int bid = blockIdx.x;
    const int p = bid / 10, pair = bid - p * 10;
    const int rg = c_rg[pair], wg = c_wg[pair];
    const int tid = threadIdx.x;
    const int base = p * CAP;

    {   // stage the 256 column boxes of this word-group
        const int j = base + (wg << 8) + tid;
        float a = cx1[j], b = cy1[j], c = cx2[j], d = cy2[j];
        sx1[tid] = a; sy1[tid] = b; sx2[tid] = c; sy2[tid] = d;
        sar[tid] = (c - a) * (d - b);
    }
    const int i = (rg << 8) + tid;
    const float ix1 = cx1[base + i], iy1 = cy1[base + i];
    const float ix2 = cx2[base + i], iy2 = cy2[base + i];
    const float iar = (ix2 - ix1) * (iy2 - iy1);
    __syncthreads();

    unsigned long long* mr = mask + ((size_t)(base + i) << 4);
    const int w0 = i >> 6;                    // wave-uniform (64 consecutive rows/wave)
#pragma unroll
    for (int ww = 0; ww < 4; ++ww) {
        const int w = (wg << 2) + ww;
        if (w < w0) continue;                 // wave-uniform skip
        unsigned long long bits = 0;
        const int jl0 = ww << 6;
        const int jg0 = w << 6;
#pragma unroll 8
        for (int jj = 0; jj < 64; ++jj) {
            const int jl = jl0 + jj;
            float ltx = fmaxf(ix1, sx1[jl]), lty = fmaxf(iy1, sy1[jl]);
            float rbx = fminf(ix2, sx2[jl]), rby = fminf(iy2, sy2[jl]);
            float wx = fmaxf(rbx - ltx, 0.f), wy = fmaxf(rby - lty, 0.f);
            float inter = wx * wy;
            float iou = inter / ((iar + sar[jl]) - inter);
            if (iou > NMS_TH && (jg0 + jj) > i) bits |= (1ull << jj);
        }
        mr[w] = bits;
    }
}

// ---------------- NMS phase 2: serial bit-scan, one wave per problem ----------------
__global__ __launch_bounds__(64) void scan_kernel(
    const unsigned long long* __restrict__ mask,
    const float* __restrict__ cx1, const float* __restrict__ cy1,
    const float* __restrict__ cx2, const float* __restrict__ cy2,
    const float* __restrict__ csc,
    float* __restrict__ svbox, float* __restrict__ svsc, int* __restrict__ svcnt) {
    __shared__ unsigned short survL[CAP];
    const int p = blockIdx.x, lane = threadIdx.x;
    const int base = p * CAP;

    unsigned long long rem = 0;   // lane l (<16) owns suppression bits j in [64l, 64l+64)
    if (lane < 16) {
        const float* sc = csc + base + (lane << 6);
        for (int b = 0; b < 64; ++b)
            if (sc[b] <= 0.f) rem |= (1ull << b);
    }

    const unsigned long long* mrow = mask + ((size_t)base << 4);
    const int wsel = lane & 15;
    unsigned long long pre[8];
#pragma unroll
    for (int r = 0; r < 8; ++r) pre[r] = mrow[(r << 4) + wsel];

    int ns = 0;
    for (int g = 0; g < 128; ++g) {
        unsigned long long cur[8];
#pragma unroll
        for (int r = 0; r < 8; ++r) cur[r] = pre[r];
        if (g < 127) {
            const unsigned long long* nx = mrow + ((size_t)(g + 1) << 7);
#pragma unroll
            for (int r = 0; r < 8; ++r) pre[r] = nx[(r << 4) + wsel];
        }
#pragma unroll
        for (int r = 0; r < 8; ++r) {
            const int i = (g << 3) + r;
            const int w = i >> 6, b = i & 63;
            bool hit = (lane == w) && (((rem >> b) & 1ull) != 0ull);
            if (__ballot(hit) == 0ull) {     // box i alive -> accept
                rem |= cur[r];
                if (lane == 0) survL[ns] = (unsigned short)i;
                ++ns;
            }
        }
    }
    __syncthreads();
    for (int s = lane; s < ns; s += 64) {
        int r = survL[s];
        int o = base + s;
        svsc[o] = csc[base + r];
        svbox[(size_t)o * 4 + 0] = cx1[base + r];
        svbox[(size_t)o * 4 + 1] = cy1[base + r];
        svbox[(size_t)o * 4 + 2] = cx2[base + r];
        svbox[(size_t)o * 4 + 3] = cy2[base + r];
    }
    if (lane == 0) svcnt[p] = ns;
}

// ---------------- merge 5 survivor lists per image by score (ties -> lower level) ----------------
__global__ __launch_bounds__(256) void merge_kernel(
    const float* __restrict__ svbox, const float* __restrict__ svsc,
    const int* __restrict__ svcnt, float* __restrict__ out) {
    __shared__ float sls[NLVL][CAP];
    __shared__ int scnt[NLVL];
    const int img = blockIdx.x, tid = threadIdx.x;
    if (tid < NLVL) scnt[tid] = svcnt[img * NLVL + tid];
    __syncthreads();
    for (int l = 0; l < NLVL; ++l) {
        int c = scnt[l];
        for (int i = tid; i < c; i += 256) sls[l][i] = svsc[(img * NLVL + l) * CAP + i];
    }
    __syncthreads();
    for (int l = 0; l < NLVL; ++l) {
        int c = scnt[l];
        for (int i = tid; i < c; i += 256) {
            float s = sls[l][i];
            int pos = i;
            for (int m = 0; m < NLVL; ++m) {
                if (m == l) continue;
                int n2 = scnt[m];
                int lo = 0, hi = n2;
                if (m < l) {
                    while (lo < hi) { int mid = (lo + hi) >> 1; if (sls[m][mid] >= s) lo = mid + 1; else hi = mid; }
                } else {
                    while (lo < hi) { int mid = (lo + hi) >> 1; if (sls[m][mid] > s)  lo = mid + 1; else hi = mid; }
                }
                pos += lo;
            }
            if (pos < POST_N) {
                int src = (img * NLVL + l) * CAP + i;
                float* o = out + ((size_t)img * POST_N + pos) * 5;
                o[0] = svbox[(size_t)src * 4 + 0];
                o[1] = svbox[(size_t)src * 4 + 1];
                o[2] = svbox[(size_t)src * 4 + 2];
                o[3] = svbox[(size_t)src * 4 + 3];
                o[4] = s;
            }
        }
    }
}

extern "C" void kernel_launch(void* const* d_in, const int* in_sizes, int n_in,
                              void* d_out, int out_size, void* d_ws, size_t ws_size,
                              hipStream_t stream) {
    const float* obj     = (const float*)d_in[0];
    const float* deltas  = (const float*)d_in[1];
    const float* anchors = (const float*)d_in[2];
    float* out = (float*)d_out;

    char* w = (char*)d_ws;
    size_t off = 0;
    auto alloc = [&](size_t bytes) -> void* {
        void* pp = w + off;
        off += (bytes + 511) & ~(size_t)511;
        return pp;
    };
    unsigned* ghist = (unsigned*)alloc((size_t)NPROB * HBINS * 4);
    unsigned* b1buf = (unsigned*)alloc((size_t)NPROB * 4);
    int*      ccnt  = (int*)alloc((size_t)NPROB * 4);
    unsigned long long* cand = (unsigned long long*)alloc((size_t)NPROB * CCAP * 8);
    unsigned* sel = (unsigned*)alloc((size_t)NPROB * CAP * 4);
    float* cx1 = (float*)alloc((size_t)NPROB * CAP * 4);
    float* cy1 = (float*)alloc((size_t)NPROB * CAP * 4);
    float* cx2 = (float*)alloc((size_t)NPROB * CAP * 4);
    float* cy2 = (float*)alloc((size_t)NPROB * CAP * 4);
    float* csc = (float*)alloc((size_t)NPROB * CAP * 4);
    float* svbox = (float*)alloc((size_t)NPROB * CAP * 16);
    float* svsc  = (float*)alloc((size_t)NPROB * CAP * 4);
    int*   svcnt = (int*)alloc((size_t)NPROB * 4);
    unsigned long long* nmask = (unsigned long long*)alloc((size_t)NPROB * CAP * 16 * 8);
    if (off > ws_size) return;  // fail cleanly (output stays poisoned -> visible failure)

    hipMemsetAsync(ghist, 0, (size_t)NPROB * HBINS * 4, stream);
    hipMemsetAsync(ccnt, 0, (size_t)NPROB * 4, stream);
    hipMemsetAsync(d_out, 0, (size_t)out_size * sizeof(float), stream);

    hist_kernel<<<NBATCH * NCHUNK, 256, 0, stream>>>(obj, ghist);
    pick1_kernel<<<NPROB, 256, 0, stream>>>(ghist, b1buf);
    compact_kernel<<<NBATCH * NCHUNK, 256, 0, stream>>>(obj, b1buf, ccnt, cand);
    rank_kernel<<<NPROB * 16, 256, 0, stream>>>(cand, ccnt, sel);
    decode_kernel<<<(NPROB * CAP) / 256, 256, 0, stream>>>(obj, deltas, anchors, sel,
                                                           cx1, cy1, cx2, cy2, csc);
    mask_kernel<<<NPROB * 10, 256, 0, stream>>>(cx1, cy1, cx2, cy2, nmask);
    scan_kernel<<<NPROB, 64, 0, stream>>>(nmask, cx1, cy1, cx2, cy2, csc, svbox, svsc, svcnt);
    merge_kernel<<<NBATCH, 256, 0, stream>>>(svbox, svsc, svcnt, out);
}